// Round 1
// baseline (226.476 us; speedup 1.0000x reference)
//
#include <hip/hip_runtime.h>
#include <cstdint>

// Problem constants: B=4, S=512, D=512, H=8, TM=20, DH=64
// out layout: out[1048576] | attn[8388608] | reg[1] | T_i[2048]  (all float)

__device__ __forceinline__ float sep_mad(float a, float b, float c) {
    // (a*b) rounded, then +c rounded -- matches numpy's separate mul/add,
    // prevents -ffp-contract=fast from fusing to FMA (spike threshold is discontinuous).
    float t = a * b;
    asm volatile("" : "+v"(t));
    return t + c;
}

// ---------------- Kernel 1: gate MLPs -> T_i ----------------
__global__ __launch_bounds__(64) void k_gates(
    const float* __restrict__ x,
    const float* __restrict__ gw1, const float* __restrict__ gb1,
    const float* __restrict__ gw2, const float* __restrict__ gb2,
    const float* __restrict__ gw3, const float* __restrict__ gb3,
    const float* __restrict__ cw1, const float* __restrict__ cb1,
    const float* __restrict__ cw2, const float* __restrict__ cb2,
    int* __restrict__ Ti, float* __restrict__ ti_out)
{
    __shared__ float xs[512];
    __shared__ float h1s[64];
    __shared__ float h2s[32];
    __shared__ float chs[32];
    const int tok = blockIdx.x;
    const int t = threadIdx.x;
    const float* xr = x + tok * 512;

    float4* xs4 = (float4*)xs;
    xs4[t]      = ((const float4*)xr)[t];
    xs4[t + 64] = ((const float4*)xr)[t + 64];
    __syncthreads();

    // h1[t] = relu(dot(gw1[t], x) + gb1[t])   (64 outputs, one per thread)
    {
        const float4* w4 = (const float4*)(gw1 + t * 512);
        float a = gb1[t];
        for (int k = 0; k < 128; k++) {
            float4 wv = w4[k];
            float4 xv = xs4[k];
            a = fmaf(wv.x, xv.x, a); a = fmaf(wv.y, xv.y, a);
            a = fmaf(wv.z, xv.z, a); a = fmaf(wv.w, xv.w, a);
        }
        h1s[t] = fmaxf(a, 0.f);
    }
    // ch[t] = relu(dot(cw1[t], x) + cb1[t])   (32 outputs, threads 0..31)
    if (t < 32) {
        const float4* w4 = (const float4*)(cw1 + t * 512);
        float a = cb1[t];
        for (int k = 0; k < 128; k++) {
            float4 wv = w4[k];
            float4 xv = xs4[k];
            a = fmaf(wv.x, xv.x, a); a = fmaf(wv.y, xv.y, a);
            a = fmaf(wv.z, xv.z, a); a = fmaf(wv.w, xv.w, a);
        }
        chs[t] = fmaxf(a, 0.f);
    }
    __syncthreads();
    if (t < 32) {
        const float* w2 = gw2 + t * 64;
        float a = gb2[t];
        for (int k = 0; k < 64; k++) a = fmaf(w2[k], h1s[k], a);
        h2s[t] = fmaxf(a, 0.f);
    }
    __syncthreads();
    if (t == 0) {
        float gg = gb3[0], cc = cb2[0];
        for (int k = 0; k < 32; k++) {
            gg = fmaf(gw3[k], h2s[k], gg);
            cc = fmaf(cw2[k], chs[k], cc);
        }
        float g = 1.f / (1.f + expf(-gg));
        float c = 1.f / (1.f + expf(-cc));
        float p1 = 0.7f * g, p2 = 0.3f * c;
        asm volatile("" : "+v"(p1), "+v"(p2));
        float comb = p1 + p2;
        float tf = ceilf(comb * 20.0f);
        tf = fminf(fmaxf(tf, 1.f), 20.f);
        Ti[tok] = (int)tf;
        ti_out[tok] = tf;
    }
}

// ---------------- Kernel 2: tiled fp32 SGEMM, Y = X @ W^T (+bias) ----------------
// M=2048, N=512, K=512. grid = (N/64, M/64, nmat). BM=BN=64, BK=16, 256 thr, 4x4 micro.
__global__ __launch_bounds__(256) void k_sgemm(
    const float* __restrict__ X,
    const float* __restrict__ W0, const float* __restrict__ W1, const float* __restrict__ W2,
    const float* __restrict__ bias,
    float* __restrict__ Y0, float* __restrict__ Y1, float* __restrict__ Y2,
    int hasBias)
{
    __shared__ float Xs[16][68];   // [kk][row], pad 68 keeps 16B align + 2-way-max store conflicts
    __shared__ float Ws[16][68];
    const float* W = (blockIdx.z == 0) ? W0 : ((blockIdx.z == 1) ? W1 : W2);
    float* Y       = (blockIdx.z == 0) ? Y0 : ((blockIdx.z == 1) ? Y1 : Y2);
    const int bn = blockIdx.x * 64, bm = blockIdx.y * 64;
    const int tid = threadIdx.x;
    const int ty = tid >> 4, tx = tid & 15;
    const int lr = tid >> 2;          // 0..63
    const int lc = (tid & 3) * 4;     // 0,4,8,12

    float acc[4][4] = {};

    for (int k0 = 0; k0 < 512; k0 += 16) {
        float4 xa = *(const float4*)(X + (bm + lr) * 512 + k0 + lc);
        float4 wa = *(const float4*)(W + (bn + lr) * 512 + k0 + lc);
        __syncthreads();
        Xs[lc + 0][lr] = xa.x; Xs[lc + 1][lr] = xa.y; Xs[lc + 2][lr] = xa.z; Xs[lc + 3][lr] = xa.w;
        Ws[lc + 0][lr] = wa.x; Ws[lc + 1][lr] = wa.y; Ws[lc + 2][lr] = wa.z; Ws[lc + 3][lr] = wa.w;
        __syncthreads();
#pragma unroll
        for (int kk = 0; kk < 16; kk++) {
            float4 xv = *(const float4*)&Xs[kk][ty * 4];
            float4 wv = *(const float4*)&Ws[kk][tx * 4];
            acc[0][0] = fmaf(xv.x, wv.x, acc[0][0]); acc[0][1] = fmaf(xv.x, wv.y, acc[0][1]);
            acc[0][2] = fmaf(xv.x, wv.z, acc[0][2]); acc[0][3] = fmaf(xv.x, wv.w, acc[0][3]);
            acc[1][0] = fmaf(xv.y, wv.x, acc[1][0]); acc[1][1] = fmaf(xv.y, wv.y, acc[1][1]);
            acc[1][2] = fmaf(xv.y, wv.z, acc[1][2]); acc[1][3] = fmaf(xv.y, wv.w, acc[1][3]);
            acc[2][0] = fmaf(xv.z, wv.x, acc[2][0]); acc[2][1] = fmaf(xv.z, wv.y, acc[2][1]);
            acc[2][2] = fmaf(xv.z, wv.z, acc[2][2]); acc[2][3] = fmaf(xv.z, wv.w, acc[2][3]);
            acc[3][0] = fmaf(xv.w, wv.x, acc[3][0]); acc[3][1] = fmaf(xv.w, wv.y, acc[3][1]);
            acc[3][2] = fmaf(xv.w, wv.z, acc[3][2]); acc[3][3] = fmaf(xv.w, wv.w, acc[3][3]);
        }
    }

    float b0 = 0.f, b1 = 0.f, b2 = 0.f, b3 = 0.f;
    if (hasBias) {
        b0 = bias[bn + tx * 4 + 0]; b1 = bias[bn + tx * 4 + 1];
        b2 = bias[bn + tx * 4 + 2]; b3 = bias[bn + tx * 4 + 3];
    }
#pragma unroll
    for (int u = 0; u < 4; u++) {
        int m = bm + ty * 4 + u;
        float4 o;
        o.x = acc[u][0] + b0; o.y = acc[u][1] + b1; o.z = acc[u][2] + b2; o.w = acc[u][3] + b3;
        *(float4*)(Y + m * 512 + bn + tx * 4) = o;
    }
}

// ---------------- Kernel 3: LIF + ballot bit-pack + v spike counts ----------------
// One wave per (token, head). lanes = 64 dims of the head.
__global__ __launch_bounds__(256) void k_lif(
    const float* __restrict__ qkv,           // [3][2048][512]
    const int* __restrict__ Ti,
    const float* __restrict__ pAlpha, const float* __restrict__ pBeta,
    unsigned long long* __restrict__ qbits,  // [(b*8+h)*20 + t]*512 + s
    unsigned long long* __restrict__ kbits,
    float* __restrict__ vmean)               // [tok*512 + h*64 + d]
{
    const int wid = threadIdx.x >> 6, lane = threadIdx.x & 63;
    const int flat = blockIdx.x * 4 + wid;   // 0..16383 = (b,s,h)
    const int tok = flat >> 3, h = flat & 7;
    const int b = tok >> 9, s = tok & 511;
    const float alpha = pAlpha[0], beta = pBeta[0];
    const int T = Ti[tok];
    const int off = tok * 512 + h * 64 + lane;
    const float xq = qkv[off];
    const float xk = qkv[off + 1048576];
    const float xv = qkv[off + 2097152];
    float iq = 0.f, vq = 0.f, ik = 0.f, vk = 0.f, iv = 0.f, vv = 0.f;
    int cnt = 0;
    const int base = ((b * 8 + h) * 20) * 512 + s;
#pragma unroll
    for (int t = 0; t < 20; t++) {
        iq = sep_mad(alpha, iq, xq); vq = sep_mad(beta, vq, iq);
        bool sq = vq >= 1.0f; vq = sq ? 0.f : vq;
        ik = sep_mad(alpha, ik, xk); vk = sep_mad(beta, vk, ik);
        bool sk = vk >= 1.0f; vk = sk ? 0.f : vk;
        iv = sep_mad(alpha, iv, xv); vv = sep_mad(beta, vv, iv);
        bool sv = vv >= 1.0f; vv = sv ? 0.f : vv;
        bool act = t < T;
        unsigned long long mq = __ballot(sq && act);
        unsigned long long mk = __ballot(sk && act);
        if (lane == 0) {
            qbits[base + t * 512] = mq;
            kbits[base + t * 512] = mk;
        }
        cnt += (sv && act) ? 1 : 0;
    }
    vmean[off] = (float)cnt / 20.0f;
}

// ---------------- Kernel 4: popcount scores + softmax -> attn ----------------
// Block handles (b,h) and 4 rows i. 256 threads.
__global__ __launch_bounds__(256) void k_scores(
    const unsigned long long* __restrict__ qbits,
    const unsigned long long* __restrict__ kbits,
    float* __restrict__ attn)
{
    const int bh = blockIdx.x >> 7;            // 0..31
    const int i0 = (blockIdx.x & 127) * 4;
    const int base = bh * 20 * 512;
    __shared__ unsigned long long qs[4][20];
    __shared__ float sc[4][512];
    const int tid = threadIdx.x;
    if (tid < 80) {
        int r = tid / 20, t = tid % 20;
        qs[r][t] = qbits[base + t * 512 + i0 + r];
    }
    __syncthreads();
#pragma unroll
    for (int pass = 0; pass < 2; pass++) {
        int j = tid + pass * 256;
        unsigned long long kb[20];
#pragma unroll
        for (int t = 0; t < 20; t++) kb[t] = kbits[base + t * 512 + j];
        int c0 = 0, c1 = 0, c2 = 0, c3 = 0;
#pragma unroll
        for (int t = 0; t < 20; t++) {
            unsigned long long kv = kb[t];
            c0 += __popcll(qs[0][t] & kv);
            c1 += __popcll(qs[1][t] & kv);
            c2 += __popcll(qs[2][t] & kv);
            c3 += __popcll(qs[3][t] & kv);
        }
        sc[0][j] = (float)c0 * 0.125f;
        sc[1][j] = (float)c1 * 0.125f;
        sc[2][j] = (float)c2 * 0.125f;
        sc[3][j] = (float)c3 * 0.125f;
    }
    __syncthreads();
    // one wave per row: softmax over 512
    const int r = tid >> 6, lane = tid & 63;
    float vals[8];
    float m = -1e30f;
#pragma unroll
    for (int k = 0; k < 8; k++) { vals[k] = sc[r][lane + 64 * k]; m = fmaxf(m, vals[k]); }
#pragma unroll
    for (int off = 32; off; off >>= 1) m = fmaxf(m, __shfl_xor(m, off));
    float sum = 0.f;
#pragma unroll
    for (int k = 0; k < 8; k++) { vals[k] = expf(vals[k] - m); sum += vals[k]; }
#pragma unroll
    for (int off = 32; off; off >>= 1) sum += __shfl_xor(sum, off);
    float* arow = attn + ((long)bh * 512 + (i0 + r)) * 512;
#pragma unroll
    for (int k = 0; k < 8; k++) arow[lane + 64 * k] = vals[k] / sum;
}

// ---------------- Kernel 5: head_out = attn @ v_mean (batched per b,h) ----------------
// grid = B*H*(S/64) = 256 blocks, 256 threads; out tile 64(i) x 64(d), K=j=512.
__global__ __launch_bounds__(256) void k_av(
    const float* __restrict__ attn,
    const float* __restrict__ vmean,   // [tok][512] token-major
    float* __restrict__ hout)          // [tok][512] cols = h*64+d
{
    const int bh = blockIdx.x >> 3;
    const int i0 = (blockIdx.x & 7) * 64;
    const int b = bh >> 3, h = bh & 7;
    __shared__ float As[64][68];   // [j][i]
    __shared__ float Vs[64][64];   // [j][d]
    const int tid = threadIdx.x;
    const int ty = tid >> 4, tx = tid & 15;
    const int alr = tid >> 2;          // 0..63  (i row)
    const int alc = (tid & 3) * 4;     // 0..12  (j within 16)
    const int vlr = tid >> 4;          // 0..15  (j row)
    const int vlc = (tid & 15) * 4;    // 0..60  (d)
    const long abase = ((long)bh * 512 + i0) * 512;
    float acc[4][4] = {};

    for (int j0 = 0; j0 < 512; j0 += 64) {
        float4 aload[4], vload[4];
#pragma unroll
        for (int jc = 0; jc < 4; jc++)
            aload[jc] = *(const float4*)(attn + abase + alr * 512 + j0 + jc * 16 + alc);
#pragma unroll
        for (int rr = 0; rr < 4; rr++)
            vload[rr] = *(const float4*)(vmean + (b * 512 + j0 + vlr + 16 * rr) * 512 + h * 64 + vlc);
        __syncthreads();
#pragma unroll
        for (int jc = 0; jc < 4; jc++) {
            int jl = jc * 16 + alc;
            As[jl + 0][alr] = aload[jc].x; As[jl + 1][alr] = aload[jc].y;
            As[jl + 2][alr] = aload[jc].z; As[jl + 3][alr] = aload[jc].w;
        }
#pragma unroll
        for (int rr = 0; rr < 4; rr++)
            *(float4*)&Vs[vlr + 16 * rr][vlc] = vload[rr];
        __syncthreads();
#pragma unroll
        for (int kk = 0; kk < 64; kk++) {
            float4 a4 = *(const float4*)&As[kk][ty * 4];
            float4 v4 = *(const float4*)&Vs[kk][tx * 4];
            acc[0][0] = fmaf(a4.x, v4.x, acc[0][0]); acc[0][1] = fmaf(a4.x, v4.y, acc[0][1]);
            acc[0][2] = fmaf(a4.x, v4.z, acc[0][2]); acc[0][3] = fmaf(a4.x, v4.w, acc[0][3]);
            acc[1][0] = fmaf(a4.y, v4.x, acc[1][0]); acc[1][1] = fmaf(a4.y, v4.y, acc[1][1]);
            acc[1][2] = fmaf(a4.y, v4.z, acc[1][2]); acc[1][3] = fmaf(a4.y, v4.w, acc[1][3]);
            acc[2][0] = fmaf(a4.z, v4.x, acc[2][0]); acc[2][1] = fmaf(a4.z, v4.y, acc[2][1]);
            acc[2][2] = fmaf(a4.z, v4.z, acc[2][2]); acc[2][3] = fmaf(a4.z, v4.w, acc[2][3]);
            acc[3][0] = fmaf(a4.w, v4.x, acc[3][0]); acc[3][1] = fmaf(a4.w, v4.y, acc[3][1]);
            acc[3][2] = fmaf(a4.w, v4.z, acc[3][2]); acc[3][3] = fmaf(a4.w, v4.w, acc[3][3]);
        }
    }
#pragma unroll
    for (int u = 0; u < 4; u++) {
        int i = i0 + ty * 4 + u;
        float4 o; o.x = acc[u][0]; o.y = acc[u][1]; o.z = acc[u][2]; o.w = acc[u][3];
        *(float4*)(hout + (b * 512 + i) * 512 + h * 64 + tx * 4) = o;
    }
}

// ---------------- Kernel 6: reg scalar ----------------
__global__ __launch_bounds__(256) void k_reg(const int* __restrict__ Ti, float* __restrict__ out)
{
    __shared__ int red[256];
    int t = threadIdx.x, s = 0;
    for (int k = t; k < 2048; k += 256) s += Ti[k];
    red[t] = s; __syncthreads();
    for (int off = 128; off; off >>= 1) {
        if (t < off) red[t] += red[t + off];
        __syncthreads();
    }
    if (t == 0) out[0] = 1e-3f * ((float)red[0] / 2048.0f);
}

extern "C" void kernel_launch(void* const* d_in, const int* in_sizes, int n_in,
                              void* d_out, int out_size, void* d_ws, size_t ws_size,
                              hipStream_t stream)
{
    const float* x    = (const float*)d_in[0];
    const float* Wq   = (const float*)d_in[1];
    const float* Wk   = (const float*)d_in[2];
    const float* Wv   = (const float*)d_in[3];
    const float* Wo   = (const float*)d_in[4];
    const float* bo   = (const float*)d_in[5];
    const float* gw1  = (const float*)d_in[6];
    const float* gb1  = (const float*)d_in[7];
    const float* gw2  = (const float*)d_in[8];
    const float* gb2  = (const float*)d_in[9];
    const float* gw3  = (const float*)d_in[10];
    const float* gb3  = (const float*)d_in[11];
    const float* cw1  = (const float*)d_in[12];
    const float* cb1  = (const float*)d_in[13];
    const float* cw2  = (const float*)d_in[14];
    const float* cb2  = (const float*)d_in[15];
    const float* alpha = (const float*)d_in[16];
    const float* beta  = (const float*)d_in[17];

    float* out   = (float*)d_out;                 // [2048*512]
    float* attn  = out + 1048576;                 // [32][512][512] (b*H+h major)
    float* regp  = out + 1048576 + 8388608;
    float* tiout = regp + 1;

    char* ws = (char*)d_ws;
    float* qkv = (float*)ws;                                           // 12 MB
    unsigned long long* qb = (unsigned long long*)(ws + 12582912);     // 2.62 MB
    unsigned long long* kb = (unsigned long long*)(ws + 12582912 + 2621440);
    float* vmean = (float*)(ws + 12582912 + 2 * 2621440);              // 4 MB
    float* hout  = (float*)(ws + 12582912 + 2 * 2621440 + 4194304);    // 4 MB
    int*   Ti    = (int*)  (ws + 12582912 + 2 * 2621440 + 2 * 4194304);

    k_gates<<<2048, 64, 0, stream>>>(x, gw1, gb1, gw2, gb2, gw3, gb3,
                                     cw1, cb1, cw2, cb2, Ti, tiout);
    k_sgemm<<<dim3(8, 32, 3), 256, 0, stream>>>(x, Wq, Wk, Wv, nullptr,
                                                qkv, qkv + 1048576, qkv + 2097152, 0);
    k_lif<<<4096, 256, 0, stream>>>(qkv, Ti, alpha, beta, qb, kb, vmean);
    k_scores<<<4096, 256, 0, stream>>>(qb, kb, attn);
    k_av<<<256, 256, 0, stream>>>(attn, vmean, hout);
    k_sgemm<<<dim3(8, 32, 1), 256, 0, stream>>>(hout, Wo, Wo, Wo, bo, out, out, out, 1);
    k_reg<<<1, 256, 0, stream>>>(Ti, regp);
}

// Round 2
// 179.915 us; speedup vs baseline: 1.2588x; 1.2588x over previous
//
#include <hip/hip_runtime.h>
#include <cstdint>

// Problem constants: B=4, S=512, D=512, H=8, TM=20, DH=64
// out layout: out[1048576] | attn[8388608] | reg[1] | T_i[2048]  (all float)

__device__ __forceinline__ float sep_mad(float a, float b, float c) {
    // (a*b) rounded, then +c rounded -- matches numpy's separate mul/add,
    // prevents -ffp-contract=fast from fusing to FMA (spike threshold is discontinuous).
    float t = a * b;
    asm volatile("" : "+v"(t));
    return t + c;
}

// ---------------- Kernel 1: fused gate MLPs -> T_i ----------------
// 8 tokens per block, 256 threads. Layer1 outputs padded 96->128 (o>=96 lanes idle-ish).
__global__ __launch_bounds__(256) void k_gates(
    const float* __restrict__ x,
    const float* __restrict__ gw1, const float* __restrict__ gb1,
    const float* __restrict__ gw2, const float* __restrict__ gb2,
    const float* __restrict__ gw3, const float* __restrict__ gb3,
    const float* __restrict__ cw1, const float* __restrict__ cb1,
    const float* __restrict__ cw2, const float* __restrict__ cb2,
    int* __restrict__ Ti, float* __restrict__ ti_out)
{
    __shared__ float xs[8][516];    // 8 tokens x 512 (pad 4 keeps rows 16B aligned)
    __shared__ float h1s[8][100];   // 96 hidden (64 g + 32 c)
    __shared__ float h2s[8][36];
    const int tok0 = blockIdx.x * 8;
    const int tid = threadIdx.x;

    // stage x tile: 8*512 floats = 1024 float4, 4 per thread
    for (int i = tid; i < 1024; i += 256) {
        int tok = i >> 7, c4 = i & 127;
        *(float4*)&xs[tok][c4 * 4] = ((const float4*)(x + (tok0 + tok) * 512))[c4];
    }
    __syncthreads();

    // layer 1: 96 outputs (pad to 128), tg in {0,1} covers 4 tokens each
    {
        const int o = tid & 127;
        const int tg = tid >> 7;
        const int oc = (o < 96) ? o : 95;
        const float4* wrow = (const float4*)((oc < 64) ? (gw1 + oc * 512) : (cw1 + (oc - 64) * 512));
        const float bias = (oc < 64) ? gb1[oc] : cb1[oc - 64];
        float acc[4];
#pragma unroll
        for (int t = 0; t < 4; t++) acc[t] = bias;
        for (int k4 = 0; k4 < 128; k4++) {
            float4 w4 = wrow[k4];
#pragma unroll
            for (int t = 0; t < 4; t++) {
                float4 x4 = *(const float4*)&xs[tg * 4 + t][k4 * 4];
                acc[t] = fmaf(w4.x, x4.x, acc[t]); acc[t] = fmaf(w4.y, x4.y, acc[t]);
                acc[t] = fmaf(w4.z, x4.z, acc[t]); acc[t] = fmaf(w4.w, x4.w, acc[t]);
            }
        }
        if (o < 96) {
#pragma unroll
            for (int t = 0; t < 4; t++) h1s[tg * 4 + t][o] = fmaxf(acc[t], 0.f);
        }
    }
    __syncthreads();
    // layer 2: 8 tokens x 32 outs = 256 dots of 64 (one per thread)
    {
        const int tok = tid >> 5, o2 = tid & 31;
        const float* w2 = gw2 + o2 * 64;
        float a = gb2[o2];
        for (int k = 0; k < 64; k++) a = fmaf(w2[k], h1s[tok][k], a);
        h2s[tok][o2] = fmaxf(a, 0.f);
    }
    __syncthreads();
    // layer 3 + sigmoid + combine
    if (tid < 8) {
        const int tok = tid;
        float gg = gb3[0], cc = cb2[0];
        for (int k = 0; k < 32; k++) {
            gg = fmaf(gw3[k], h2s[tok][k], gg);
            cc = fmaf(cw2[k], h1s[tok][64 + k], cc);
        }
        float g = 1.f / (1.f + expf(-gg));
        float c = 1.f / (1.f + expf(-cc));
        float p1 = 0.7f * g, p2 = 0.3f * c;
        asm volatile("" : "+v"(p1), "+v"(p2));
        float comb = p1 + p2;
        float tf = ceilf(comb * 20.0f);
        tf = fminf(fmaxf(tf, 1.f), 20.f);
        Ti[tok0 + tok] = (int)tf;
        ti_out[tok0 + tok] = tf;
    }
}

// ---------------- Kernel 2: tiled fp32 SGEMM, Y = X @ W^T (+bias), reg-prefetch ----------------
// M=2048, N=512, K=512. grid = (N/64, M/64, nmat). BM=BN=64, BK=16, 256 thr, 4x4 micro.
__global__ __launch_bounds__(256) void k_sgemm(
    const float* __restrict__ X,
    const float* __restrict__ W0, const float* __restrict__ W1, const float* __restrict__ W2,
    const float* __restrict__ bias,
    float* __restrict__ Y0, float* __restrict__ Y1, float* __restrict__ Y2,
    int hasBias)
{
    __shared__ float Xs[16][68];
    __shared__ float Ws[16][68];
    const float* W = (blockIdx.z == 0) ? W0 : ((blockIdx.z == 1) ? W1 : W2);
    float* Y       = (blockIdx.z == 0) ? Y0 : ((blockIdx.z == 1) ? Y1 : Y2);
    const int bn = blockIdx.x * 64, bm = blockIdx.y * 64;
    const int tid = threadIdx.x;
    const int ty = tid >> 4, tx = tid & 15;
    const int lr = tid >> 2;          // 0..63
    const int lc = (tid & 3) * 4;     // 0,4,8,12

    float acc[4][4] = {};
    // prefetch k0 = 0
    float4 xa = *(const float4*)(X + (bm + lr) * 512 + lc);
    float4 wa = *(const float4*)(W + (bn + lr) * 512 + lc);

    for (int k0 = 0; k0 < 512; k0 += 16) {
        __syncthreads();   // prev-iter readers done
        Xs[lc + 0][lr] = xa.x; Xs[lc + 1][lr] = xa.y; Xs[lc + 2][lr] = xa.z; Xs[lc + 3][lr] = xa.w;
        Ws[lc + 0][lr] = wa.x; Ws[lc + 1][lr] = wa.y; Ws[lc + 2][lr] = wa.z; Ws[lc + 3][lr] = wa.w;
        __syncthreads();
        // prefetch next tile (wraps harmlessly on last iter)
        const int kn = (k0 + 16) & 511;
        xa = *(const float4*)(X + (bm + lr) * 512 + kn + lc);
        wa = *(const float4*)(W + (bn + lr) * 512 + kn + lc);
#pragma unroll
        for (int kk = 0; kk < 16; kk++) {
            float4 xv = *(const float4*)&Xs[kk][ty * 4];
            float4 wv = *(const float4*)&Ws[kk][tx * 4];
            acc[0][0] = fmaf(xv.x, wv.x, acc[0][0]); acc[0][1] = fmaf(xv.x, wv.y, acc[0][1]);
            acc[0][2] = fmaf(xv.x, wv.z, acc[0][2]); acc[0][3] = fmaf(xv.x, wv.w, acc[0][3]);
            acc[1][0] = fmaf(xv.y, wv.x, acc[1][0]); acc[1][1] = fmaf(xv.y, wv.y, acc[1][1]);
            acc[1][2] = fmaf(xv.y, wv.z, acc[1][2]); acc[1][3] = fmaf(xv.y, wv.w, acc[1][3]);
            acc[2][0] = fmaf(xv.z, wv.x, acc[2][0]); acc[2][1] = fmaf(xv.z, wv.y, acc[2][1]);
            acc[2][2] = fmaf(xv.z, wv.z, acc[2][2]); acc[2][3] = fmaf(xv.z, wv.w, acc[2][3]);
            acc[3][0] = fmaf(xv.w, wv.x, acc[3][0]); acc[3][1] = fmaf(xv.w, wv.y, acc[3][1]);
            acc[3][2] = fmaf(xv.w, wv.z, acc[3][2]); acc[3][3] = fmaf(xv.w, wv.w, acc[3][3]);
        }
    }

    float b0 = 0.f, b1 = 0.f, b2 = 0.f, b3 = 0.f;
    if (hasBias) {
        b0 = bias[bn + tx * 4 + 0]; b1 = bias[bn + tx * 4 + 1];
        b2 = bias[bn + tx * 4 + 2]; b3 = bias[bn + tx * 4 + 3];
    }
#pragma unroll
    for (int u = 0; u < 4; u++) {
        int m = bm + ty * 4 + u;
        float4 o;
        o.x = acc[u][0] + b0; o.y = acc[u][1] + b1; o.z = acc[u][2] + b2; o.w = acc[u][3] + b3;
        *(float4*)(Y + m * 512 + bn + tx * 4) = o;
    }
}

// ---------------- Kernel 3: LIF + ballot bit-pack + v spike counts ----------------
__global__ __launch_bounds__(256) void k_lif(
    const float* __restrict__ qkv,           // [3][2048][512]
    const int* __restrict__ Ti,
    const float* __restrict__ pAlpha, const float* __restrict__ pBeta,
    unsigned long long* __restrict__ qbits,  // [(b*8+h)*20 + t]*512 + s
    unsigned long long* __restrict__ kbits,
    float* __restrict__ vmean)               // [tok*512 + h*64 + d]
{
    const int wid = threadIdx.x >> 6, lane = threadIdx.x & 63;
    const int flat = blockIdx.x * 4 + wid;   // (b,s,h)
    const int tok = flat >> 3, h = flat & 7;
    const int b = tok >> 9, s = tok & 511;
    const float alpha = pAlpha[0], beta = pBeta[0];
    const int T = Ti[tok];
    const int off = tok * 512 + h * 64 + lane;
    const float xq = qkv[off];
    const float xk = qkv[off + 1048576];
    const float xv = qkv[off + 2097152];
    float iq = 0.f, vq = 0.f, ik = 0.f, vk = 0.f, iv = 0.f, vv = 0.f;
    int cnt = 0;
    const int base = ((b * 8 + h) * 20) * 512 + s;
#pragma unroll
    for (int t = 0; t < 20; t++) {
        iq = sep_mad(alpha, iq, xq); vq = sep_mad(beta, vq, iq);
        bool sq = vq >= 1.0f; vq = sq ? 0.f : vq;
        ik = sep_mad(alpha, ik, xk); vk = sep_mad(beta, vk, ik);
        bool sk = vk >= 1.0f; vk = sk ? 0.f : vk;
        iv = sep_mad(alpha, iv, xv); vv = sep_mad(beta, vv, iv);
        bool sv = vv >= 1.0f; vv = sv ? 0.f : vv;
        bool act = t < T;
        unsigned long long mq = __ballot(sq && act);
        unsigned long long mk = __ballot(sk && act);
        if (lane == 0) {
            qbits[base + t * 512] = mq;
            kbits[base + t * 512] = mk;
        }
        cnt += (sv && act) ? 1 : 0;
    }
    vmean[off] = (float)cnt / 20.0f;
}

// ---------------- Kernel 4: popcount scores + softmax -> attn (+fused reg) ----------------
// Block handles (b,h) and 16 rows i. grid = 32*32 = 1024, 256 threads.
__global__ __launch_bounds__(256) void k_scores(
    const unsigned long long* __restrict__ qbits,
    const unsigned long long* __restrict__ kbits,
    float* __restrict__ attn,
    const int* __restrict__ Ti, float* __restrict__ regp)
{
    const int bh = blockIdx.x >> 5;            // 0..31
    const int i0 = (blockIdx.x & 31) * 16;
    const int base = bh * 20 * 512;
    __shared__ unsigned long long qs[20][16];
    __shared__ float sc[16][512];
    const int tid = threadIdx.x;
    for (int idx = tid; idx < 320; idx += 256) {
        int t = idx >> 4, r = idx & 15;
        qs[t][r] = qbits[base + t * 512 + i0 + r];
    }
    __syncthreads();

    {
        const unsigned long long* kbp = kbits + base + tid;
        int acc0[16] = {}, acc1[16] = {};
#pragma unroll
        for (int tc = 0; tc < 4; tc++) {
            unsigned long long kv0[5], kv1[5];
#pragma unroll
            for (int t = 0; t < 5; t++) {
                kv0[t] = kbp[(tc * 5 + t) * 512];
                kv1[t] = kbp[(tc * 5 + t) * 512 + 256];
            }
#pragma unroll
            for (int r = 0; r < 16; r++) {
#pragma unroll
                for (int t = 0; t < 5; t++) {
                    unsigned long long qv = qs[tc * 5 + t][r];
                    acc0[r] += __popcll(qv & kv0[t]);
                    acc1[r] += __popcll(qv & kv1[t]);
                }
            }
        }
#pragma unroll
        for (int r = 0; r < 16; r++) {
            sc[r][tid] = (float)acc0[r] * 0.125f;
            sc[r][tid + 256] = (float)acc1[r] * 0.125f;
        }
    }
    __syncthreads();

    // softmax: 4 waves x 4 rows each
    const int wid = tid >> 6, lane = tid & 63;
#pragma unroll
    for (int rr = 0; rr < 4; rr++) {
        const int r = wid * 4 + rr;
        float vals[8];
        float m = -1e30f;
#pragma unroll
        for (int k = 0; k < 8; k++) { vals[k] = sc[r][lane + 64 * k]; m = fmaxf(m, vals[k]); }
#pragma unroll
        for (int off = 32; off; off >>= 1) m = fmaxf(m, __shfl_xor(m, off));
        float sum = 0.f;
#pragma unroll
        for (int k = 0; k < 8; k++) { vals[k] = expf(vals[k] - m); sum += vals[k]; }
#pragma unroll
        for (int off = 32; off; off >>= 1) sum += __shfl_xor(sum, off);
        float* arow = attn + ((long)bh * 512 + (i0 + r)) * 512;
#pragma unroll
        for (int k = 0; k < 8; k++) arow[lane + 64 * k] = vals[k] / sum;
    }

    // fused reg scalar (block 0, one wave)
    if (blockIdx.x == 0 && tid < 64) {
        int s = 0;
        for (int k = tid; k < 2048; k += 64) s += Ti[k];
#pragma unroll
        for (int off = 32; off; off >>= 1) s += __shfl_xor(s, off);
        if (tid == 0) regp[0] = 1e-3f * ((float)s / 2048.0f);
    }
}

// ---------------- Kernel 5: head_out = attn @ v_mean (batched per b,h), reg-prefetch ----------------
__global__ __launch_bounds__(256) void k_av(
    const float* __restrict__ attn,
    const float* __restrict__ vmean,   // [tok][512] token-major
    float* __restrict__ hout)          // [tok][512] cols = h*64+d
{
    const int bh = blockIdx.x >> 3;
    const int i0 = (blockIdx.x & 7) * 64;
    const int b = bh >> 3, h = bh & 7;
    __shared__ float As[64][68];   // [j][i]
    __shared__ float Vs[64][64];   // [j][d]
    const int tid = threadIdx.x;
    const int ty = tid >> 4, tx = tid & 15;
    const int alr = tid >> 2;          // 0..63  (i row)
    const int alc = (tid & 3) * 4;     // 0..12  (j within 16)
    const int vlr = tid >> 4;          // 0..15  (j row)
    const int vlc = (tid & 15) * 4;    // 0..60  (d)
    const long abase = ((long)bh * 512 + i0) * 512;
    float acc[4][4] = {};

    float4 aload[4], vload[4];
#pragma unroll
    for (int jc = 0; jc < 4; jc++)
        aload[jc] = *(const float4*)(attn + abase + alr * 512 + jc * 16 + alc);
#pragma unroll
    for (int rr = 0; rr < 4; rr++)
        vload[rr] = *(const float4*)(vmean + (b * 512 + vlr + 16 * rr) * 512 + h * 64 + vlc);

    for (int j0 = 0; j0 < 512; j0 += 64) {
        __syncthreads();
#pragma unroll
        for (int jc = 0; jc < 4; jc++) {
            int jl = jc * 16 + alc;
            As[jl + 0][alr] = aload[jc].x; As[jl + 1][alr] = aload[jc].y;
            As[jl + 2][alr] = aload[jc].z; As[jl + 3][alr] = aload[jc].w;
        }
#pragma unroll
        for (int rr = 0; rr < 4; rr++)
            *(float4*)&Vs[vlr + 16 * rr][vlc] = vload[rr];
        __syncthreads();
        const int jn = (j0 + 64) & 511;   // wraps harmlessly on last iter
#pragma unroll
        for (int jc = 0; jc < 4; jc++)
            aload[jc] = *(const float4*)(attn + abase + alr * 512 + jn + jc * 16 + alc);
#pragma unroll
        for (int rr = 0; rr < 4; rr++)
            vload[rr] = *(const float4*)(vmean + (b * 512 + jn + vlr + 16 * rr) * 512 + h * 64 + vlc);
#pragma unroll
        for (int kk = 0; kk < 64; kk++) {
            float4 a4 = *(const float4*)&As[kk][ty * 4];
            float4 v4 = *(const float4*)&Vs[kk][tx * 4];
            acc[0][0] = fmaf(a4.x, v4.x, acc[0][0]); acc[0][1] = fmaf(a4.x, v4.y, acc[0][1]);
            acc[0][2] = fmaf(a4.x, v4.z, acc[0][2]); acc[0][3] = fmaf(a4.x, v4.w, acc[0][3]);
            acc[1][0] = fmaf(a4.y, v4.x, acc[1][0]); acc[1][1] = fmaf(a4.y, v4.y, acc[1][1]);
            acc[1][2] = fmaf(a4.y, v4.z, acc[1][2]); acc[1][3] = fmaf(a4.y, v4.w, acc[1][3]);
            acc[2][0] = fmaf(a4.z, v4.x, acc[2][0]); acc[2][1] = fmaf(a4.z, v4.y, acc[2][1]);
            acc[2][2] = fmaf(a4.z, v4.z, acc[2][2]); acc[2][3] = fmaf(a4.z, v4.w, acc[2][3]);
            acc[3][0] = fmaf(a4.w, v4.x, acc[3][0]); acc[3][1] = fmaf(a4.w, v4.y, acc[3][1]);
            acc[3][2] = fmaf(a4.w, v4.z, acc[3][2]); acc[3][3] = fmaf(a4.w, v4.w, acc[3][3]);
        }
    }
#pragma unroll
    for (int u = 0; u < 4; u++) {
        int i = i0 + ty * 4 + u;
        float4 o; o.x = acc[u][0]; o.y = acc[u][1]; o.z = acc[u][2]; o.w = acc[u][3];
        *(float4*)(hout + (b * 512 + i) * 512 + h * 64 + tx * 4) = o;
    }
}

extern "C" void kernel_launch(void* const* d_in, const int* in_sizes, int n_in,
                              void* d_out, int out_size, void* d_ws, size_t ws_size,
                              hipStream_t stream)
{
    const float* x    = (const float*)d_in[0];
    const float* Wq   = (const float*)d_in[1];
    const float* Wk   = (const float*)d_in[2];
    const float* Wv   = (const float*)d_in[3];
    const float* Wo   = (const float*)d_in[4];
    const float* bo   = (const float*)d_in[5];
    const float* gw1  = (const float*)d_in[6];
    const float* gb1  = (const float*)d_in[7];
    const float* gw2  = (const float*)d_in[8];
    const float* gb2  = (const float*)d_in[9];
    const float* gw3  = (const float*)d_in[10];
    const float* gb3  = (const float*)d_in[11];
    const float* cw1  = (const float*)d_in[12];
    const float* cb1  = (const float*)d_in[13];
    const float* cw2  = (const float*)d_in[14];
    const float* cb2  = (const float*)d_in[15];
    const float* alpha = (const float*)d_in[16];
    const float* beta  = (const float*)d_in[17];

    float* out   = (float*)d_out;                 // [2048*512]
    float* attn  = out + 1048576;                 // [32][512][512]
    float* regp  = out + 1048576 + 8388608;
    float* tiout = regp + 1;

    char* ws = (char*)d_ws;
    float* qkv = (float*)ws;                                           // 12 MB
    unsigned long long* qb = (unsigned long long*)(ws + 12582912);     // 2.62 MB
    unsigned long long* kb = (unsigned long long*)(ws + 12582912 + 2621440);
    float* vmean = (float*)(ws + 12582912 + 2 * 2621440);              // 4 MB
    float* hout  = (float*)(ws + 12582912 + 2 * 2621440 + 4194304);    // 4 MB
    int*   Ti    = (int*)  (ws + 12582912 + 2 * 2621440 + 2 * 4194304);

    k_gates<<<256, 256, 0, stream>>>(x, gw1, gb1, gw2, gb2, gw3, gb3,
                                     cw1, cb1, cw2, cb2, Ti, tiout);
    k_sgemm<<<dim3(8, 32, 3), 256, 0, stream>>>(x, Wq, Wk, Wv, nullptr,
                                                qkv, qkv + 1048576, qkv + 2097152, 0);
    k_lif<<<4096, 256, 0, stream>>>(qkv, Ti, alpha, beta, qb, kb, vmean);
    k_scores<<<1024, 256, 0, stream>>>(qb, kb, attn, Ti, regp);
    k_av<<<256, 256, 0, stream>>>(attn, vmean, hout);
    k_sgemm<<<dim3(8, 32, 1), 256, 0, stream>>>(hout, Wo, Wo, Wo, bo, out, out, out, 1);
}